// Round 1
// baseline (7591.280 us; speedup 1.0000x reference)
//
#include <hip/hip_runtime.h>

#define BB 4
#define LL 4096
#define DD 256

// ---------------------------------------------------------------------------
// Kernel 1: fused QKV projection. One block per (b,l) row, 256 threads.
// Thread t computes q[row,t], k[row,t], v[row,t] = dot(x[row,:], W*[t,:]).
// W rows are read strided across lanes but are tiny (256 KB each) -> L2-hot.
// ---------------------------------------------------------------------------
__global__ __launch_bounds__(256) void qkv_proj_kernel(
    const float* __restrict__ x, const float* __restrict__ Wq,
    const float* __restrict__ Wk, const float* __restrict__ Wv,
    float* __restrict__ q, float* __restrict__ k, float* __restrict__ v)
{
    __shared__ float xrow[DD];
    const int row = blockIdx.x;
    const int t = threadIdx.x;
    xrow[t] = x[(size_t)row * DD + t];
    __syncthreads();
    const float4* xr4 = reinterpret_cast<const float4*>(xrow);
    const float4* wq4 = reinterpret_cast<const float4*>(Wq + (size_t)t * DD);
    const float4* wk4 = reinterpret_cast<const float4*>(Wk + (size_t)t * DD);
    const float4* wv4 = reinterpret_cast<const float4*>(Wv + (size_t)t * DD);
    float aq = 0.f, ak = 0.f, av = 0.f;
    #pragma unroll 4
    for (int e = 0; e < DD / 4; ++e) {
        float4 xe = xr4[e];
        float4 a = wq4[e];
        float4 b = wk4[e];
        float4 c = wv4[e];
        aq += xe.x * a.x + xe.y * a.y + xe.z * a.z + xe.w * a.w;
        ak += xe.x * b.x + xe.y * b.y + xe.z * b.z + xe.w * b.w;
        av += xe.x * c.x + xe.y * c.y + xe.z * c.z + xe.w * c.w;
    }
    q[(size_t)row * DD + t] = aq;
    k[(size_t)row * DD + t] = ak;
    v[(size_t)row * DD + t] = av;
}

// ---------------------------------------------------------------------------
// Kernel 2: causal ReLU attention, flash-style (no L x L materialization).
// One block per (b,l) q-row, 256 threads. Per 256-key chunk:
//   phase 1: thread t computes s = relu(dot(q_row, k[m0+t])) / max(l,1) -> LDS
//   phase 2: thread t (= dim d) accumulates ctx[d] += s[j] * v[m0+j, d]
// Phase-2 v reads are fully coalesced; phase-1 k reads are per-thread
// sequential rows (L1/L2-served; k per batch = 4 MB).
// ---------------------------------------------------------------------------
__global__ __launch_bounds__(256) void attn_kernel(
    const float* __restrict__ q, const float* __restrict__ k,
    const float* __restrict__ v, float* __restrict__ ctx)
{
    const int row = blockIdx.x;
    const int b = row / LL;
    const int l = row % LL;
    const int t = threadIdx.x;
    __shared__ float qrow[DD];
    __shared__ float s[256];
    qrow[t] = q[(size_t)row * DD + t];
    const float* kb = k + (size_t)b * LL * DD;
    const float* vb = v + (size_t)b * LL * DD;
    const float inv = 1.0f / (float)((l > 1) ? l : 1);
    float acc = 0.f;
    for (int m0 = 0; m0 <= l; m0 += 256) {
        __syncthreads();   // protects qrow (iter 0) and s reuse (iter >0)
        const int m = m0 + t;
        float dot = 0.f;
        if (m <= l) {
            const float4* kr4 = reinterpret_cast<const float4*>(kb + (size_t)m * DD);
            const float4* qr4 = reinterpret_cast<const float4*>(qrow);
            #pragma unroll 8
            for (int e = 0; e < DD / 4; ++e) {
                float4 qe = qr4[e];
                float4 ke = kr4[e];
                dot += qe.x * ke.x + qe.y * ke.y + qe.z * ke.z + qe.w * ke.w;
            }
            dot = fmaxf(dot, 0.f) * inv;
        }
        s[t] = (m <= l) ? dot : 0.f;
        __syncthreads();
        const int mmax = min(256, l - m0 + 1);
        const float* vp = vb + (size_t)m0 * DD + t;
        #pragma unroll 4
        for (int j = 0; j < mmax; ++j) {
            acc += s[j] * vp[(size_t)j * DD];
        }
    }
    ctx[(size_t)row * DD + t] = acc;
}

// ---------------------------------------------------------------------------
// Kernel 3: output projection, same shape as kernel 1.
// ---------------------------------------------------------------------------
__global__ __launch_bounds__(256) void out_proj_kernel(
    const float* __restrict__ ctx, const float* __restrict__ Wo,
    float* __restrict__ out)
{
    __shared__ float crow[DD];
    const int row = blockIdx.x;
    const int t = threadIdx.x;
    crow[t] = ctx[(size_t)row * DD + t];
    __syncthreads();
    const float4* c4 = reinterpret_cast<const float4*>(crow);
    const float4* w4 = reinterpret_cast<const float4*>(Wo + (size_t)t * DD);
    float a = 0.f;
    #pragma unroll 4
    for (int e = 0; e < DD / 4; ++e) {
        float4 ce = c4[e];
        float4 we = w4[e];
        a += ce.x * we.x + ce.y * we.y + ce.z * we.z + ce.w * we.w;
    }
    out[(size_t)row * DD + t] = a;
}

extern "C" void kernel_launch(void* const* d_in, const int* in_sizes, int n_in,
                              void* d_out, int out_size, void* d_ws, size_t ws_size,
                              hipStream_t stream)
{
    const float* x  = (const float*)d_in[0];
    const float* Wq = (const float*)d_in[1];
    const float* Wk = (const float*)d_in[2];
    const float* Wv = (const float*)d_in[3];
    const float* Wo = (const float*)d_in[4];
    float* out = (float*)d_out;

    const size_t n = (size_t)BB * LL * DD;  // 4,194,304 elements
    float* q   = (float*)d_ws;              // [B,L,D]
    float* k   = q + n;                     // [B,L,D]
    float* v   = k + n;                     // [B,L,D]
    float* ctx = v + n;                     // [B,L,D]   total 67.1 MB of d_ws

    dim3 grid(BB * LL);
    dim3 block(256);
    qkv_proj_kernel<<<grid, block, 0, stream>>>(x, Wq, Wk, Wv, q, k, v);
    attn_kernel<<<grid, block, 0, stream>>>(q, k, v, ctx);
    out_proj_kernel<<<grid, block, 0, stream>>>(ctx, Wo, out);
}

// Round 2
// 617.461 us; speedup vs baseline: 12.2943x; 12.2943x over previous
//
#include <hip/hip_runtime.h>

#define BB 4
#define LL 4096
#define DD 256

typedef short bf16x8 __attribute__((ext_vector_type(8)));
typedef float f32x4 __attribute__((ext_vector_type(4)));
typedef unsigned short u16;

__device__ inline u16 f2b(float f) {
    union { float f; unsigned u; } v; v.f = f;
    unsigned r = (v.u + 0x7fffu + ((v.u >> 16) & 1u)) >> 16;  // RNE
    return (u16)r;
}

__device__ inline f32x4 mfma16(bf16x8 a, bf16x8 b, f32x4 c) {
    return __builtin_amdgcn_mfma_f32_16x16x32_bf16(a, b, c, 0, 0, 0);
}

// ---------------------------------------------------------------------------
// Kernel 0: convert the 4 weight matrices fp32 -> bf16. 65536 threads.
// ---------------------------------------------------------------------------
__global__ __launch_bounds__(256) void wconv_kernel(
    const float* __restrict__ Wq, const float* __restrict__ Wk,
    const float* __restrict__ Wv, const float* __restrict__ Wo,
    u16* __restrict__ wqb, u16* __restrict__ wkb,
    u16* __restrict__ wvb, u16* __restrict__ wob)
{
    int i = blockIdx.x * 256 + threadIdx.x;   // 0 .. 65535
    wqb[i] = f2b(Wq[i]);
    wkb[i] = f2b(Wk[i]);
    wvb[i] = f2b(Wv[i]);
    wob[i] = f2b(Wo[i]);
}

// ---------------------------------------------------------------------------
// Kernel 1: fused QKV projection via MFMA. One block = 4 waves = 64 M-rows.
// Wave w computes rows [blk*64 + 16w, +16) x all 256 cols for Wq, Wk, Wv.
// NT GEMM: C[m][n] = sum_k x[m][k] * W[n][k]; both operands k-contiguous.
// A-frag: lane(m=ln, k=8*q4+j); B-frag: lane(n=ln, k=8*q4+j);
// C/D: col=lane&15, row=4*(lane>>4)+reg.
// V is stored TRANSPOSED: vtb[b][d][l], so attention PV B-frags are
// contiguous.
// ---------------------------------------------------------------------------
__global__ __launch_bounds__(256) void qkv_kernel(
    const float* __restrict__ x,
    const u16* __restrict__ wqb, const u16* __restrict__ wkb, const u16* __restrict__ wvb,
    u16* __restrict__ qb, u16* __restrict__ kb, u16* __restrict__ vtb)
{
    const int w = threadIdx.x >> 6, lane = threadIdx.x & 63;
    const int q4 = lane >> 4, ln = lane & 15;
    const int m_base = blockIdx.x * 64 + w * 16;

    // A-fragments for this wave's 16 rows, all K=256 (8 frags), fp32->bf16
    bf16x8 a[8];
    const float* xrow = x + (size_t)(m_base + ln) * DD;
    #pragma unroll
    for (int ks = 0; ks < 8; ++ks) {
        const float4* p = (const float4*)(xrow + ks * 32 + q4 * 8);
        float4 f0 = p[0], f1 = p[1];
        bf16x8 t;
        t[0] = (short)f2b(f0.x); t[1] = (short)f2b(f0.y);
        t[2] = (short)f2b(f0.z); t[3] = (short)f2b(f0.w);
        t[4] = (short)f2b(f1.x); t[5] = (short)f2b(f1.y);
        t[6] = (short)f2b(f1.z); t[7] = (short)f2b(f1.w);
        a[ks] = t;
    }

    const u16* ws[3] = {wqb, wkb, wvb};
    for (int wi = 0; wi < 3; ++wi) {
        const u16* W = ws[wi];
        f32x4 acc[16];
        #pragma unroll
        for (int ct = 0; ct < 16; ++ct) acc[ct] = f32x4{0.f, 0.f, 0.f, 0.f};
        #pragma unroll
        for (int ks = 0; ks < 8; ++ks) {
            #pragma unroll
            for (int ct = 0; ct < 16; ++ct) {
                bf16x8 bf = *(const bf16x8*)(W + (size_t)(ct * 16 + ln) * DD + ks * 32 + q4 * 8);
                acc[ct] = mfma16(a[ks], bf, acc[ct]);
            }
        }
        if (wi < 2) {
            u16* dst = (wi == 0) ? qb : kb;
            #pragma unroll
            for (int ct = 0; ct < 16; ++ct)
                #pragma unroll
                for (int r = 0; r < 4; ++r) {
                    int row = m_base + q4 * 4 + r;
                    int col = ct * 16 + ln;
                    dst[(size_t)row * DD + col] = f2b(acc[ct][r]);
                }
        } else {
            #pragma unroll
            for (int ct = 0; ct < 16; ++ct)
                #pragma unroll
                for (int r = 0; r < 4; ++r) {
                    int row = m_base + q4 * 4 + r;       // global M = b*L + l
                    int col = ct * 16 + ln;              // d
                    int bb = row >> 12, l = row & 4095;
                    vtb[(size_t)bb * (DD * LL) + (size_t)col * LL + l] = f2b(acc[ct][r]);
                }
        }
    }
}

// ---------------------------------------------------------------------------
// Kernel 2: causal ReLU attention, MFMA flash-style.
// 256 blocks (one per CU): block = (batch b, pair p). Handles q-tiles
// t0 = p and t1 = 127-p (32 rows each) -> constant 129 k-tile units/block.
// Per k-tile (32 k-rows):
//   S  = Q Kt    (4 waves each own one 16x16 quadrant per q-tile; K-frags
//                 straight from global/L2, shared across both q-tiles)
//   P  = relu(mask(S)) / max(l,1)  -> bf16 -> LDS (C-layout -> A-layout)
//   O += P V     (V^T-frags straight from global/L2, shared across q-tiles)
// ---------------------------------------------------------------------------
#define LSTRIDE 40   // LDS row stride in shorts (padded: 80B, 16B-aligned)

__global__ __launch_bounds__(256, 1) void attn_kernel(
    const u16* __restrict__ qb, const u16* __restrict__ kb,
    const u16* __restrict__ vtb, u16* __restrict__ ctxb)
{
    __shared__ u16 ps[2][32 * LSTRIDE];

    const int p = blockIdx.x & 63, b = blockIdx.x >> 6;
    const int w = threadIdx.x >> 6, lane = threadIdx.x & 63;
    const int q4 = lane >> 4, ln = lane & 15;
    const int wr = w >> 1, wc = w & 1;
    const int t0 = p, t1 = 127 - p;

    const u16* qB = qb + (size_t)b * LL * DD;
    const u16* kB = kb + (size_t)b * LL * DD;
    const u16* vB = vtb + (size_t)b * DD * LL;

    // Q A-fragments, resident: per q-tile, rows [32*t + 16*wr, +16)
    bf16x8 aQ[2][8];
    {
        const u16* q0 = qB + (size_t)(t0 * 32 + wr * 16 + ln) * DD;
        const u16* q1 = qB + (size_t)(t1 * 32 + wr * 16 + ln) * DD;
        #pragma unroll
        for (int ks = 0; ks < 8; ++ks) {
            aQ[0][ks] = *(const bf16x8*)(q0 + ks * 32 + q4 * 8);
            aQ[1][ks] = *(const bf16x8*)(q1 + ks * 32 + q4 * 8);
        }
    }

    f32x4 oacc[2][8];
    #pragma unroll
    for (int i = 0; i < 2; ++i)
        #pragma unroll
        for (int tt = 0; tt < 8; ++tt) oacc[i][tt] = f32x4{0.f, 0.f, 0.f, 0.f};

    float inv[2][4];
    #pragma unroll
    for (int r = 0; r < 4; ++r) {
        int r0 = t0 * 32 + wr * 16 + q4 * 4 + r;
        int r1 = t1 * 32 + wr * 16 + q4 * 4 + r;
        inv[0][r] = 1.0f / (float)(r0 > 1 ? r0 : 1);
        inv[1][r] = 1.0f / (float)(r1 > 1 ? r1 : 1);
    }

    for (int kt = 0; kt <= t1; ++kt) {
        const bool a0 = (kt <= t0);

        // ---- S phase: K-frags shared between both q-tiles ----
        f32x4 s0 = f32x4{0.f, 0.f, 0.f, 0.f};
        f32x4 s1 = f32x4{0.f, 0.f, 0.f, 0.f};
        const u16* krow = kB + (size_t)(kt * 32 + wc * 16 + ln) * DD;
        #pragma unroll
        for (int ks = 0; ks < 8; ++ks) {
            bf16x8 bk = *(const bf16x8*)(krow + ks * 32 + q4 * 8);
            s1 = mfma16(aQ[1][ks], bk, s1);
            if (a0) s0 = mfma16(aQ[0][ks], bk, s0);
        }

        // ---- mask / relu / scale -> LDS (bf16, A-layout staging) ----
        {
            const int rowl = wr * 16 + q4 * 4;   // +r
            const int coll = wc * 16 + ln;
            bool diag1 = (kt == t1);
            #pragma unroll
            for (int r = 0; r < 4; ++r) {
                float v1 = fmaxf(s1[r], 0.f) * inv[1][r];
                if (diag1 && (coll > rowl + r)) v1 = 0.f;
                ps[1][(rowl + r) * LSTRIDE + coll] = f2b(v1);
            }
            if (a0) {
                bool diag0 = (kt == t0);
                #pragma unroll
                for (int r = 0; r < 4; ++r) {
                    float v0 = fmaxf(s0[r], 0.f) * inv[0][r];
                    if (diag0 && (coll > rowl + r)) v0 = 0.f;
                    ps[0][(rowl + r) * LSTRIDE + coll] = f2b(v0);
                }
            }
        }
        __syncthreads();

        // ---- PV phase: V^T-frags shared between both q-tiles ----
        bf16x8 ap1 = *(const bf16x8*)(&ps[1][(wr * 16 + ln) * LSTRIDE + q4 * 8]);
        bf16x8 ap0;
        if (a0) ap0 = *(const bf16x8*)(&ps[0][(wr * 16 + ln) * LSTRIDE + q4 * 8]);
        #pragma unroll
        for (int tt = 0; tt < 8; ++tt) {
            bf16x8 bv = *(const bf16x8*)(vB + (size_t)(wc * 128 + tt * 16 + ln) * LL + kt * 32 + q4 * 8);
            oacc[1][tt] = mfma16(ap1, bv, oacc[1][tt]);
            if (a0) oacc[0][tt] = mfma16(ap0, bv, oacc[0][tt]);
        }
        __syncthreads();   // protect ps against next iteration's writes
    }

    // ---- epilogue: store ctx (bf16) ----
    const int tt_arr[2] = {t0, t1};
    #pragma unroll
    for (int i = 0; i < 2; ++i)
        #pragma unroll
        for (int tt = 0; tt < 8; ++tt)
            #pragma unroll
            for (int r = 0; r < 4; ++r) {
                int row = tt_arr[i] * 32 + wr * 16 + q4 * 4 + r;
                int col = wc * 128 + tt * 16 + ln;
                ctxb[((size_t)b * LL + row) * DD + col] = f2b(oacc[i][tt][r]);
            }
}

// ---------------------------------------------------------------------------
// Kernel 3: output projection via MFMA (ctx bf16 @ Wo^T), fp32 store.
// ---------------------------------------------------------------------------
__global__ __launch_bounds__(256) void oproj_kernel(
    const u16* __restrict__ ctxb, const u16* __restrict__ wob,
    float* __restrict__ out)
{
    const int w = threadIdx.x >> 6, lane = threadIdx.x & 63;
    const int q4 = lane >> 4, ln = lane & 15;
    const int m_base = blockIdx.x * 64 + w * 16;

    bf16x8 a[8];
    const u16* crow = ctxb + (size_t)(m_base + ln) * DD;
    #pragma unroll
    for (int ks = 0; ks < 8; ++ks)
        a[ks] = *(const bf16x8*)(crow + ks * 32 + q4 * 8);

    f32x4 acc[16];
    #pragma unroll
    for (int ct = 0; ct < 16; ++ct) acc[ct] = f32x4{0.f, 0.f, 0.f, 0.f};
    #pragma unroll
    for (int ks = 0; ks < 8; ++ks) {
        #pragma unroll
        for (int ct = 0; ct < 16; ++ct) {
            bf16x8 bf = *(const bf16x8*)(wob + (size_t)(ct * 16 + ln) * DD + ks * 32 + q4 * 8);
            acc[ct] = mfma16(a[ks], bf, acc[ct]);
        }
    }
    #pragma unroll
    for (int ct = 0; ct < 16; ++ct)
        #pragma unroll
        for (int r = 0; r < 4; ++r) {
            int row = m_base + q4 * 4 + r;
            int col = ct * 16 + ln;
            out[(size_t)row * DD + col] = acc[ct][r];
        }
}

extern "C" void kernel_launch(void* const* d_in, const int* in_sizes, int n_in,
                              void* d_out, int out_size, void* d_ws, size_t ws_size,
                              hipStream_t stream)
{
    const float* x  = (const float*)d_in[0];
    const float* Wq = (const float*)d_in[1];
    const float* Wk = (const float*)d_in[2];
    const float* Wv = (const float*)d_in[3];
    const float* Wo = (const float*)d_in[4];
    float* out = (float*)d_out;

    const size_t nW = (size_t)DD * DD;        // 65536
    const size_t nX = (size_t)BB * LL * DD;   // 4,194,304

    u16* wqb  = (u16*)d_ws;
    u16* wkb  = wqb + nW;
    u16* wvb  = wkb + nW;
    u16* wob  = wvb + nW;
    u16* qb   = wob + nW;
    u16* kb   = qb + nX;
    u16* vtb  = kb + nX;        // transposed: [B][D][L]
    u16* ctxb = vtb + nX;       // total ~34 MB

    wconv_kernel<<<dim3(DD * DD / 256), dim3(256), 0, stream>>>(
        Wq, Wk, Wv, Wo, wqb, wkb, wvb, wob);
    qkv_kernel<<<dim3(BB * LL / 64), dim3(256), 0, stream>>>(
        x, wqb, wkb, wvb, qb, kb, vtb);
    attn_kernel<<<dim3(256), dim3(256), 0, stream>>>(qb, kb, vtb, ctxb);
    oproj_kernel<<<dim3(BB * LL / 64), dim3(256), 0, stream>>>(ctxb, wob, out);
}